// Round 2
// baseline (293.644 us; speedup 1.0000x reference)
//
#include <hip/hip_runtime.h>
#include <math.h>

#define BATCH 32768
#define NE 9
#define RANK 50
#define DIM 450            // NE * RANK
#define REL_DIM 900        // 2 * DIM

__device__ __forceinline__ float softplusf(float x) {
    return (x > 20.f) ? x : log1pf(expf(x));
}
__device__ __forceinline__ float phif(float z) {
    return 0.5f * (1.f + erff(z * 0.70710678118654752f));
}

// One 64-lane wave per sample.
__global__ __launch_bounds__(64) void k_main(
    const int* __restrict__ queries, const int* __restrict__ these_queries,
    const float* __restrict__ entity, const float* __restrict__ rel,
    const float* __restrict__ rel_diag, const float* __restrict__ bh,
    const float* __restrict__ bt, const float* __restrict__ c_param,
    const float* __restrict__ cnn_w, const float* __restrict__ cnn_b,
    const float* __restrict__ h2e_w, const float* __restrict__ h2e_b,
    const float* __restrict__ cnnn_w, const float* __restrict__ cnnn_b,
    const float* __restrict__ h2en_w, const float* __restrict__ h2en_b,
    const float* __restrict__ noise,
    float* __restrict__ y_out, float* __restrict__ ws_rows)
{
    const int b = blockIdx.x;
    const int l = threadIdx.x;

    __shared__ __align__(16) float xs[1352];   // head (450) ++ rel_q (900), contiguous image
    __shared__ float feat[128], featn[128];
    __shared__ float cont[228];                // 225 Givens pair contribs
    __shared__ float clean_s[NE], stdv_s[NE], noisy_s[NE], score_s[NE];
    __shared__ int   sidx[2];
    __shared__ float sg[2];
    __shared__ float sthr[2];                  // [0]=thr_in (3rd), [1]=thr_out (2nd)

    const int q0 = queries[b * 3 + 0];
    const int q1 = queries[b * 3 + 1];
    const int t2 = these_queries[b * 3 + 2];

    const float2* hp2  = (const float2*)(entity   + (size_t)q0 * DIM);     // 8B aligned (1800B rows)
    const float4* rp4  = (const float4*)(rel      + (size_t)q1 * REL_DIM); // 16B aligned (3600B rows)
    const float2* rd2p = (const float2*)(rel_diag + (size_t)q1 * DIM);
    const float2* rh2p = (const float2*)(entity   + (size_t)t2 * DIM);

    // ---- issue ALL global loads early (latency hidden behind conv) ----
    float2 h2[4]; float4 r4[4]; float2 rd2[4], rh2[4];
#pragma unroll
    for (int k = 0; k < 4; ++k) { int i = l + 64 * k; if (i < 225) h2[k] = hp2[i]; }
#pragma unroll
    for (int k = 0; k < 4; ++k) { int i = l + 64 * k; if (i < 225) r4[k] = rp4[i]; }
#pragma unroll
    for (int k = 0; k < 4; ++k) { int u = l + 64 * k; if (u < 225) { rd2[k] = rd2p[u]; rh2[k] = rh2p[u]; } }
    float nz = 0.f;
    if (l < NE) nz = noise[(size_t)b * NE + l];

    // ---- stage x = [head ; rel] into LDS ----
    float2* xs2 = (float2*)xs;
#pragma unroll
    for (int k = 0; k < 4; ++k) { int i = l + 64 * k; if (i < 225) xs2[i] = h2[k]; }
#pragma unroll
    for (int k = 0; k < 4; ++k) {
        int i = l + 64 * k;
        if (i < 225) {
            float4 v = r4[k];
            xs2[225 + 2 * i]     = make_float2(v.x, v.y);
            xs2[225 + 2 * i + 1] = make_float2(v.z, v.w);
        }
    }
    __syncthreads();

    // ---- two 5x5 stride-3 VALID convs over (27,50); 2 outputs/lane each ----
    float fr[2], fnr[2];
    const float cb0 = cnn_b[0], cb1 = cnnn_b[0];
#pragma unroll
    for (int rep = 0; rep < 2; ++rep) {
        int o = l + rep * 64;
        int oh = o >> 4, ow = o & 15;
        const float* base = xs + (oh * 3) * RANK + ow * 3;
        float a0 = cb0, a1 = cb1;
#pragma unroll
        for (int i = 0; i < 5; ++i)
#pragma unroll
            for (int j = 0; j < 5; ++j) {
                float v = base[i * RANK + j];
                a0 = fmaf(v, cnn_w[i * 5 + j], a0);   // uniform addr -> s_load
                a1 = fmaf(v, cnnn_w[i * 5 + j], a1);
            }
        fr[rep] = a0; fnr[rep] = a1;
    }
    feat[l] = fr[0];  feat[l + 64] = fr[1];
    featn[l] = fnr[0]; featn[l + 64] = fnr[1];

    // ---- Givens + dist2 pair contribs for ALL 9 experts (225 units, 4/lane) ----
#pragma unroll
    for (int k = 0; k < 4; ++k) {
        int u = l + 64 * k;
        if (u < 225) {
            int e = u / 25, i = u - e * 25;
            float2 r = rd2[k];
            float2 x = xs2[u];                       // head pair
            float nrm = fmaxf(sqrtf(r.x * r.x + r.y * r.y), 1e-15f);
            float c0 = r.x / nrm, c1 = r.y / nrm;
            float2 rl = xs2[225 + e * 50 + i];       // rel[..., :RANK] pair
            float o0 = c0 * x.x - c1 * x.y + rl.x;
            float o1 = c1 * x.x + c0 * x.y + rl.y;
            float2 rh = rh2[k];
            float d0 = o0 - rh.x, d1 = o1 - rh.y;
            cont[u] = fmaf(d0, d0, d1 * d1);
        }
    }
    __syncthreads();

    // ---- 18 dots (9 clean, 9 std) on 54 lanes: 3 chunks of <=43 each ----
    int chunk = l / 18, e18 = l - chunk * 18;
    float acc = 0.f;
    if (l < 54) {
        const float* fv   = (e18 < 9) ? feat : featn;
        const float* wrow = (e18 < 9) ? (h2e_w + e18 * 128) : (h2en_w + (e18 - 9) * 128);
        int start = chunk * 43;
#pragma unroll 8
        for (int k = 0; k < 43; ++k) {
            int o = start + k;
            if (o < 128) acc = fmaf(fv[o], wrow[o], acc);
        }
    }
    float pA = __shfl_down(acc, 18);
    float pB = __shfl_down(acc, 36);
    float tot = acc + pA + pB;                       // valid for l < 18
    if (l < 9) {
        clean_s[l] = tot + h2e_b[l];
    } else if (l < 18) {
        stdv_s[l - 9] = softplusf(tot + h2en_b[l - 9]) + 0.01f;
    } else if (l < 27) {
        // dist2 sums + scores for all 9 experts (lanes 18..26)
        int e = l - 18;
        float d2 = 0.f;
#pragma unroll
        for (int i = 0; i < 25; ++i) d2 += cont[e * 25 + i];
        float c = softplusf(c_param[q1]);
        float base = bh[q0] + bt[t2];
        score_s[e] = base - c * d2;
    }
    __syncthreads();

    if (l < NE) noisy_s[l] = fmaf(nz, stdv_s[l], clean_s[l]);
    __syncthreads();

    // ---- top-3 of 9 (ties -> lower index, matching lax.top_k) ----
    if (l == 0) {
        int i0 = -1, i1 = -1;
        float v0 = -__builtin_huge_valf(), v1 = v0, v2 = v0;
#pragma unroll
        for (int e = 0; e < NE; ++e) {
            float v = noisy_s[e];
            if (v > v0)      { v2 = v1; v1 = v0; i1 = i0; v0 = v; i0 = e; }
            else if (v > v1) { v2 = v1; v1 = v; i1 = e; }
            else if (v > v2) { v2 = v; }
        }
        float e1 = expf(v1 - v0);
        float inv = 1.f / (1.f + e1);
        sidx[0] = i0; sidx[1] = i1;
        sg[0] = inv; sg[1] = e1 * inv;
        sthr[0] = v2; sthr[1] = v1;
    }
    __syncthreads();

    // ---- epilogue: gates/probs (row-major ws), y ----
    if (l < NE) {
        float g = (l == sidx[0]) ? sg[0] : ((l == sidx[1]) ? sg[1] : 0.f);
        ws_rows[(size_t)b * 18 + l] = g;
    } else if (l < 18) {
        int e = l - 9;
        float thr_in = sthr[0], thr_out = sthr[1];
        float n = noisy_s[e];
        float thr = (n > thr_in) ? thr_in : thr_out;
        ws_rows[(size_t)b * 18 + 9 + e] = phif((clean_s[e] - thr) / stdv_s[e]);
    } else if (l == 18) {
        float s = expf(score_s[sidx[0]]) + expf(score_s[sidx[1]]);
        y_out[b] = logf((s == 0.f) ? 2.2204460492503131e-16f : s);
    }
}

// 256 blocks x 64 threads; each thread accumulates 2 rows' 18 values in regs.
__global__ __launch_bounds__(64) void k_reduce(const float* __restrict__ ws_rows,
                                               float* __restrict__ partials)
{
    const int blk = blockIdx.x, t = threadIdx.x;
    float acc[18];
#pragma unroll
    for (int j = 0; j < 18; ++j) acc[j] = 0.f;
    const int r0 = blk * 128 + t * 2;
#pragma unroll
    for (int rr = 0; rr < 2; ++rr) {
        const float2* row = (const float2*)(ws_rows + (size_t)(r0 + rr) * 18);
#pragma unroll
        for (int j = 0; j < 9; ++j) {
            float2 v = row[j];
            acc[2 * j] += v.x; acc[2 * j + 1] += v.y;
        }
    }
#pragma unroll
    for (int j = 0; j < 18; ++j) {
        float v = acc[j];
        for (int off = 32; off; off >>= 1) v += __shfl_down(v, off);
        if (t == 0) partials[blk * 18 + j] = v;
    }
}

// 1 block: stage-2 reduce of 256 partials per column + cv^2 loss.
__global__ __launch_bounds__(64) void k_loss(const float* __restrict__ partials,
                                             float* __restrict__ out)
{
    __shared__ float sums[18];
    const int t = threadIdx.x;
    if (t < 18) {
        float s = 0.f;
        for (int p = 0; p < 256; ++p) s += partials[p * 18 + t];
        sums[t] = s;
    }
    __syncthreads();
    if (t == 0) {
        float loss = 0.f;
#pragma unroll
        for (int part = 0; part < 2; ++part) {
            const float* v = sums + part * NE;   // part0: importance (gates), part1: load (prob)
            float mean = 0.f;
            for (int i = 0; i < NE; ++i) mean += v[i];
            mean /= 9.f;
            float var = 0.f;
            for (int i = 0; i < NE; ++i) { float d = v[i] - mean; var += d * d; }
            var /= 8.f;                           // ddof=1
            loss += var / (mean * mean + 1e-10f);
        }
        out[BATCH] = 0.01f * loss;
    }
}

extern "C" void kernel_launch(void* const* d_in, const int* in_sizes, int n_in,
                              void* d_out, int out_size, void* d_ws, size_t ws_size,
                              hipStream_t stream)
{
    const int*   queries = (const int*)d_in[0];
    const int*   these   = (const int*)d_in[1];
    const float* entity  = (const float*)d_in[2];
    const float* rel     = (const float*)d_in[3];
    const float* rel_dg  = (const float*)d_in[4];
    const float* bh      = (const float*)d_in[5];
    const float* bt      = (const float*)d_in[6];
    const float* c_par   = (const float*)d_in[7];
    const float* cnn_w   = (const float*)d_in[8];
    const float* cnn_b   = (const float*)d_in[9];
    const float* h2e_w   = (const float*)d_in[10];
    const float* h2e_b   = (const float*)d_in[11];
    const float* cnnn_w  = (const float*)d_in[12];
    const float* cnnn_b  = (const float*)d_in[13];
    const float* h2en_w  = (const float*)d_in[14];
    const float* h2en_b  = (const float*)d_in[15];
    const float* noise   = (const float*)d_in[16];

    float* y  = (float*)d_out;
    float* ws = (float*)d_ws;
    float* ws_rows  = ws;                                  // BATCH * 18
    float* partials = ws + (size_t)BATCH * 18;             // 256 * 18

    k_main<<<BATCH, 64, 0, stream>>>(queries, these, entity, rel, rel_dg, bh, bt, c_par,
                                     cnn_w, cnn_b, h2e_w, h2e_b, cnnn_w, cnnn_b,
                                     h2en_w, h2en_b, noise, y, ws_rows);
    k_reduce<<<256, 64, 0, stream>>>(ws_rows, partials);
    k_loss<<<1, 64, 0, stream>>>(partials, y);
}

// Round 3
// 187.431 us; speedup vs baseline: 1.5667x; 1.5667x over previous
//
#include <hip/hip_runtime.h>
#include <math.h>

#define BATCH 32768
#define NE 9
#define RANK 50
#define DIM 450            // NE * RANK
#define REL_DIM 900        // 2 * DIM
#define N_REL 22
#define EPSV 2.2204460492503131e-16f

__device__ __forceinline__ float softplusf(float x) {
    return (x > 20.f) ? x : log1pf(expf(x));
}
__device__ __forceinline__ float phif(float z) {
    return 0.5f * (1.f + erff(z * 0.70710678118654752f));
}

// Per-relation precompute: pure-rel conv outputs' dot contributions (o in [48,128)),
// Givens cos/sin table, softplus(c). 22 blocks.
__global__ __launch_bounds__(64) void k_pre(
    const float* __restrict__ rel, const float* __restrict__ rel_diag,
    const float* __restrict__ c_param,
    const float* __restrict__ cnn_w, const float* __restrict__ cnn_b,
    const float* __restrict__ cnnn_w, const float* __restrict__ cnnn_b,
    const float* __restrict__ h2e_w, const float* __restrict__ h2en_w,
    float* __restrict__ cs_tab, float* __restrict__ pre_out, float* __restrict__ c_soft)
{
    const int r = blockIdx.x;
    const int l = threadIdx.x;
    __shared__ float rl[REL_DIM];
    __shared__ float fA[80], fB[80];

    const float* relp = rel + (size_t)r * REL_DIM;
    for (int i = l; i < REL_DIM; i += 64) rl[i] = relp[i];
    __syncthreads();

    const float cb0 = cnn_b[0], cb1 = cnnn_b[0];
    for (int idx = l; idx < 80; idx += 64) {
        int o = 48 + idx;
        int oh = o >> 4, ow = o & 15;
        const float* base = rl + (oh * 3 - 9) * RANK + ow * 3;   // rel image rows
        float a0 = cb0, a1 = cb1;
#pragma unroll
        for (int i = 0; i < 5; ++i)
#pragma unroll
            for (int j = 0; j < 5; ++j) {
                float v = base[i * RANK + j];
                a0 = fmaf(v, cnn_w[i * 5 + j], a0);
                a1 = fmaf(v, cnnn_w[i * 5 + j], a1);
            }
        fA[idx] = a0; fB[idx] = a1;
    }
    __syncthreads();

    if (l < 18) {
        int e = (l < 9) ? l : (l - 9);
        const float* w = ((l < 9) ? (h2e_w + e * 128) : (h2en_w + e * 128)) + 48;
        const float* f = (l < 9) ? fA : fB;
        float acc = 0.f;
#pragma unroll 8
        for (int t = 0; t < 80; ++t) acc = fmaf(f[t], w[t], acc);
        pre_out[r * 18 + l] = acc;
    }
    if (l == 63) c_soft[r] = softplusf(c_param[r]);

    const float2* rd2 = (const float2*)(rel_diag + (size_t)r * DIM);
    float2* cs2 = (float2*)(cs_tab + (size_t)r * DIM);
    for (int u = l; u < 225; u += 64) {
        float2 v = rd2[u];
        float nrm = fmaxf(sqrtf(v.x * v.x + v.y * v.y), 1e-15f);
        cs2[u] = make_float2(v.x / nrm, v.y / nrm);
    }
}

// One 64-lane wave per sample.
__global__ __launch_bounds__(64) void k_main(
    const int* __restrict__ queries, const int* __restrict__ these_queries,
    const float* __restrict__ entity, const float* __restrict__ rel,
    const float* __restrict__ bh, const float* __restrict__ bt,
    const float* __restrict__ cnn_w, const float* __restrict__ cnn_b,
    const float* __restrict__ h2e_w, const float* __restrict__ h2e_b,
    const float* __restrict__ cnnn_w, const float* __restrict__ cnnn_b,
    const float* __restrict__ h2en_w, const float* __restrict__ h2en_b,
    const float* __restrict__ noise,
    const float* __restrict__ cs_tab, const float* __restrict__ pre_out,
    const float* __restrict__ c_soft,
    float* __restrict__ y_out, float* __restrict__ ws_rows)
{
    const int b = blockIdx.x;
    const int l = threadIdx.x;

    __shared__ __align__(16) float xs[552];     // image rows 0..10: head(450) ++ rel[0:100]
    __shared__ __align__(16) float2 fs[51];     // (feat, featn) per o<48, padded 1/16
    __shared__ float clean_s[NE], stdv_s[NE], noisy_s[NE];
    __shared__ int   sidx[2];
    __shared__ float sg[2];
    __shared__ float sthr[2];                   // [0]=thr_in (3rd), [1]=thr_out (2nd)

    const int q0 = queries[b * 3 + 0];
    const int q1 = queries[b * 3 + 1];
    const int t2 = these_queries[b * 3 + 2];

    const float2* hp2 = (const float2*)(entity + (size_t)q0 * DIM);   // 225 float2
    const float2* rp2 = (const float2*)(rel + (size_t)q1 * REL_DIM);  // need first 50

    // ---- issue staging loads early ----
    float2 h2[4];
#pragma unroll
    for (int k = 0; k < 4; ++k) { int i = l + 64 * k; if (i < 225) h2[k] = hp2[i]; }
    float2 rr2 = make_float2(0.f, 0.f);
    if (l < 50) rr2 = rp2[l];
    float nz = 0.f;
    if (l < NE) nz = noise[(size_t)b * NE + l];
    float pre_v = 0.f;
    if (l < 18) pre_v = pre_out[q1 * 18 + l];

    float2* xs2 = (float2*)xs;
#pragma unroll
    for (int k = 0; k < 4; ++k) { int i = l + 64 * k; if (i < 225) xs2[i] = h2[k]; }
    if (l < 50) xs2[225 + l] = rr2;
    __syncthreads();

    // ---- conv: sample-dependent outputs o < 48 (oh 0..2), both kernels ----
    if (l < 48) {
        int oh = l >> 4, ow = l & 15;
        const float* base = xs + (oh * 3) * RANK + ow * 3;
        float a0 = cnn_b[0], a1 = cnnn_b[0];
#pragma unroll
        for (int i = 0; i < 5; ++i)
#pragma unroll
            for (int j = 0; j < 5; ++j) {
                float v = base[i * RANK + j];
                a0 = fmaf(v, cnn_w[i * 5 + j], a0);
                a1 = fmaf(v, cnnn_w[i * 5 + j], a1);
            }
        fs[l + (l >> 4)] = make_float2(a0, a1);
    }
    __syncthreads();

    // ---- 18 dots of length 48: 54 lanes, 16 terms each ----
    float acc = 0.f;
    if (l < 54) {
        int chunk = l / 18, j = l - chunk * 18;
        int e = (j < 9) ? j : (j - 9);
        const float* wrow = ((j < 9) ? (h2e_w + e * 128) : (h2en_w + e * 128)) + chunk * 16;
        int fbase = chunk * 17;   // padded chunk base
        if (j < 9) {
#pragma unroll
            for (int k = 0; k < 16; ++k) acc = fmaf(fs[fbase + k].x, wrow[k], acc);
        } else {
#pragma unroll
            for (int k = 0; k < 16; ++k) acc = fmaf(fs[fbase + k].y, wrow[k], acc);
        }
    }
    float pA = __shfl_down(acc, 18);
    float pB = __shfl_down(acc, 36);
    float tot = acc + pA + pB;                  // valid for l < 18
    if (l < 9)        clean_s[l]     = tot + pre_v + h2e_b[l];
    else if (l < 18)  stdv_s[l - 9]  = softplusf(tot + pre_v + h2en_b[l - 9]) + 0.01f;
    __syncthreads();
    if (l < NE) noisy_s[l] = fmaf(nz, stdv_s[l], clean_s[l]);
    __syncthreads();

    // ---- top-3 of 9 (ties -> lower index, matching lax.top_k) ----
    if (l == 0) {
        int i0 = -1, i1 = -1;
        float v0 = -__builtin_huge_valf(), v1 = v0, v2 = v0;
#pragma unroll
        for (int e = 0; e < NE; ++e) {
            float v = noisy_s[e];
            if (v > v0)      { v2 = v1; v1 = v0; i1 = i0; v0 = v; i0 = e; }
            else if (v > v1) { v2 = v1; v1 = v; i1 = e; }
            else if (v > v2) { v2 = v; }
        }
        float e1 = expf(v1 - v0);
        float inv = 1.f / (1.f + e1);
        sidx[0] = i0; sidx[1] = i1;
        sg[0] = inv; sg[1] = e1 * inv;
        sthr[0] = v2; sthr[1] = v1;
    }
    __syncthreads();

    // ---- Givens + dist2 for the 2 selected experts; lanes 0-24 & 32-56 ----
    float contrib = 0.f;
    bool act = (l < 25) || (l >= 32 && l < 57);
    if (act) {
        int sel = (l >= 32) ? 1 : 0;
        int p = l - 32 * sel;
        int e = sidx[sel];
        int u = e * 25 + p;
        float2 cs = *(const float2*)(cs_tab + (size_t)q1 * DIM + 2 * u);
        float2 rl = *(const float2*)(rel + (size_t)q1 * REL_DIM + e * 100 + 2 * p);
        float2 rh = *(const float2*)(entity + (size_t)t2 * DIM + 2 * u);
        float2 x  = xs2[u];
        float o0 = cs.x * x.x - cs.y * x.y + rl.x;
        float o1 = cs.y * x.x + cs.x * x.y + rl.y;
        float d0 = o0 - rh.x, d1 = o1 - rh.y;
        contrib = fmaf(d0, d0, d1 * d1);
    }

    // ---- epilogue: gates/probs (row-major ws) while Givens loads are in flight ----
    if (l < NE) {
        float g = (l == sidx[0]) ? sg[0] : ((l == sidx[1]) ? sg[1] : 0.f);
        ws_rows[(size_t)b * 18 + l] = g;
    } else if (l < 18) {
        int e = l - 9;
        float thr_in = sthr[0], thr_out = sthr[1];
        float n = noisy_s[e];
        float thr = (n > thr_in) ? thr_in : thr_out;
        ws_rows[(size_t)b * 18 + 9 + e] = phif((clean_s[e] - thr) / stdv_s[e]);
    }

    // reduce contrib within each 32-lane half (xor stays inside the half)
#pragma unroll
    for (int off = 16; off; off >>= 1) contrib += __shfl_xor(contrib, off);
    float d2b = __shfl(contrib, 32);
    if (l == 0) {
        float c = c_soft[q1];
        float base = bh[q0] + bt[t2];
        float s = expf(base - c * contrib) + expf(base - c * d2b);
        y_out[b] = logf((s == 0.f) ? EPSV : s);
    }
}

// 256 blocks x 64 threads; each thread accumulates 2 rows' 18 values in regs.
__global__ __launch_bounds__(64) void k_reduce(const float* __restrict__ ws_rows,
                                               float* __restrict__ partials)
{
    const int blk = blockIdx.x, t = threadIdx.x;
    float acc[18];
#pragma unroll
    for (int j = 0; j < 18; ++j) acc[j] = 0.f;
    const int r0 = blk * 128 + t * 2;
#pragma unroll
    for (int rr = 0; rr < 2; ++rr) {
        const float2* row = (const float2*)(ws_rows + (size_t)(r0 + rr) * 18);
#pragma unroll
        for (int j = 0; j < 9; ++j) {
            float2 v = row[j];
            acc[2 * j] += v.x; acc[2 * j + 1] += v.y;
        }
    }
#pragma unroll
    for (int j = 0; j < 18; ++j) {
        float v = acc[j];
        for (int off = 32; off; off >>= 1) v += __shfl_down(v, off);
        if (t == 0) partials[blk * 18 + j] = v;
    }
}

// 1 block: stage-2 reduce of 256 partials per column + cv^2 loss.
__global__ __launch_bounds__(64) void k_loss(const float* __restrict__ partials,
                                             float* __restrict__ out)
{
    __shared__ float sums[18];
    const int t = threadIdx.x;
    if (t < 18) {
        float s = 0.f;
        for (int p = 0; p < 256; ++p) s += partials[p * 18 + t];
        sums[t] = s;
    }
    __syncthreads();
    if (t == 0) {
        float loss = 0.f;
#pragma unroll
        for (int part = 0; part < 2; ++part) {
            const float* v = sums + part * NE;
            float mean = 0.f;
            for (int i = 0; i < NE; ++i) mean += v[i];
            mean /= 9.f;
            float var = 0.f;
            for (int i = 0; i < NE; ++i) { float d = v[i] - mean; var += d * d; }
            var /= 8.f;                   // ddof=1
            loss += var / (mean * mean + 1e-10f);
        }
        out[BATCH] = 0.01f * loss;
    }
}

extern "C" void kernel_launch(void* const* d_in, const int* in_sizes, int n_in,
                              void* d_out, int out_size, void* d_ws, size_t ws_size,
                              hipStream_t stream)
{
    const int*   queries = (const int*)d_in[0];
    const int*   these   = (const int*)d_in[1];
    const float* entity  = (const float*)d_in[2];
    const float* rel     = (const float*)d_in[3];
    const float* rel_dg  = (const float*)d_in[4];
    const float* bh      = (const float*)d_in[5];
    const float* bt      = (const float*)d_in[6];
    const float* c_par   = (const float*)d_in[7];
    const float* cnn_w   = (const float*)d_in[8];
    const float* cnn_b   = (const float*)d_in[9];
    const float* h2e_w   = (const float*)d_in[10];
    const float* h2e_b   = (const float*)d_in[11];
    const float* cnnn_w  = (const float*)d_in[12];
    const float* cnnn_b  = (const float*)d_in[13];
    const float* h2en_w  = (const float*)d_in[14];
    const float* h2en_b  = (const float*)d_in[15];
    const float* noise   = (const float*)d_in[16];

    float* y  = (float*)d_out;
    float* ws = (float*)d_ws;
    float* ws_rows  = ws;                                     // BATCH*18
    float* partials = ws + (size_t)BATCH * 18;                // 256*18
    float* cs_tab   = partials + 256 * 18;                    // 22*450
    float* pre_out  = cs_tab + N_REL * DIM;                   // 22*18
    float* c_soft   = pre_out + N_REL * 18;                   // 22

    k_pre<<<N_REL, 64, 0, stream>>>(rel, rel_dg, c_par, cnn_w, cnn_b, cnnn_w, cnnn_b,
                                    h2e_w, h2en_w, cs_tab, pre_out, c_soft);
    k_main<<<BATCH, 64, 0, stream>>>(queries, these, entity, rel, bh, bt,
                                     cnn_w, cnn_b, h2e_w, h2e_b, cnnn_w, cnnn_b,
                                     h2en_w, h2en_b, noise, cs_tab, pre_out, c_soft,
                                     y, ws_rows);
    k_reduce<<<256, 64, 0, stream>>>(ws_rows, partials);
    k_loss<<<1, 64, 0, stream>>>(partials, y);
}